// Round 3
// baseline (412.880 us; speedup 1.0000x reference)
//
#include <hip/hip_runtime.h>
#include <hip/hip_bf16.h>

#define BB 4
#define HH 8
#define LL 2048
#define DD 64

typedef __attribute__((ext_vector_type(8))) short short8;
typedef __attribute__((ext_vector_type(4))) float floatx4;
typedef unsigned int u32;
typedef unsigned short u16;
typedef unsigned long long u64;

// 1/sqrt(DIM/HEADS) * log2(e) = (1/sqrt(8)) * 1.4426950409
#define SM_COEF 0.51006977f

// ---- K0a: transpose+convert Q,K: x[b, g*512+h*64+d, i] -> ws[g][b][h][i][d] (bf16) ----
__global__ __launch_bounds__(256) void qk_tr_kernel(const float* __restrict__ x,
                                                    unsigned short* __restrict__ ws) {
  const int b = blockIdx.z;
  const int g = blockIdx.y >> 3;   // 0 = Q, 1 = K
  const int h = blockIdx.y & 7;
  const int tid = threadIdx.x;
  const int i = blockIdx.x * 64 + (tid & 63);
  const int dq = tid >> 6;         // which 16-row d-group
  const float* src = x + ((size_t)(b * 1536 + g * 512 + h * 64 + dq * 16)) * LL + i;
  float v[16];
#pragma unroll
  for (int k = 0; k < 16; ++k) v[k] = src[(size_t)k * LL];
  __hip_bfloat16 hb[16] __attribute__((aligned(16)));
#pragma unroll
  for (int k = 0; k < 16; ++k) hb[k] = __float2bfloat16(v[k]);
  unsigned short* dst = ws + (size_t)g * ((size_t)BB * HH * LL * DD) +
                        ((size_t)(b * HH + h) * LL + i) * DD + dq * 16;
  *reinterpret_cast<short8*>(dst) = *reinterpret_cast<const short8*>(hb);
  *reinterpret_cast<short8*>(dst + 8) = *reinterpret_cast<const short8*>(hb + 8);
}

// ---- K0b: straight convert V: x[b, 1024+h*64+d, j] -> vt[b][h][d][j] (bf16) ----
__global__ __launch_bounds__(256) void v_cv_kernel(const float* __restrict__ x,
                                                   unsigned short* __restrict__ vt) {
  const size_t idx = ((size_t)blockIdx.x * 256 + threadIdx.x) * 4;  // over B*512*L floats
  const size_t row = idx >> 11;   // b*512 + (h*64+d)
  const int col = (int)(idx & 2047);
  const size_t b = row >> 9;
  const size_t r = row & 511;
  const float4 f = *reinterpret_cast<const float4*>(x + ((b * 1536 + 1024 + r) << 11) + col);
  __hip_bfloat16 hb[4] __attribute__((aligned(8)));
  hb[0] = __float2bfloat16(f.x);
  hb[1] = __float2bfloat16(f.y);
  hb[2] = __float2bfloat16(f.z);
  hb[3] = __float2bfloat16(f.w);
  *reinterpret_cast<u64*>(vt + idx) = *reinterpret_cast<const u64*>(hb);
}

// ---- K1: fused attention, BARRIER-FREE. 1024 blocks (XCD-swizzled), 4 waves x 16 rows. ----
__global__ __launch_bounds__(256, 4) void mha_main_kernel(const u16* __restrict__ qb,
                                                          const u16* __restrict__ kb,
                                                          const u16* __restrict__ vt,
                                                          float* __restrict__ out) {
  __shared__ unsigned char pls[4][2048] __attribute__((aligned(16)));  // per-wave 16x64 bf16 P

  // XCD-bijective swizzle: each XCD owns 4 consecutive (b,h) (1024 % 8 == 0)
  const int wg = blockIdx.x;
  const int lin = (wg & 7) * 128 + (wg >> 3);
  const int bh = lin >> 5;          // 0..31
  const int ib = lin & 31;          // i-block within (b,h)
  const int b = bh >> 3, h = bh & 7;

  const int tid = threadIdx.x;
  const int wave = tid >> 6, lane = tid & 63;
  const int l15 = lane & 15, g = lane >> 4;
  const int swz = (l15 & 7) << 4;
  const int itile = ib * 64 + wave * 16;

  // Q B-fragments (col = l15 -> i, k = 8*g+t -> d), kept in registers
  const u16* qrow = qb + ((size_t)bh * LL + itile + l15) * DD + 8 * g;
  const short8 qf0 = *reinterpret_cast<const short8*>(qrow);
  const short8 qf1 = *reinterpret_cast<const short8*>(qrow + 32);
  const u16* kt = kb + (size_t)bh * LL * DD + 8 * g;  // K rows [j][d], fragment base
  const u16* vbase = vt + (size_t)bh * DD * LL;       // V [d][j]

  // ---- phase 1: row sum of exp2, K direct from L2, register double-buffer ----
  short8 ka[4][2], kc[4][2];
#define LOADK(dst, t)                                                        \
  {                                                                          \
    _Pragma("unroll") for (int nt = 0; nt < 4; ++nt) {                       \
      const u16* kr = kt + (size_t)((t) * 64 + nt * 16 + l15) * DD;          \
      dst[nt][0] = *reinterpret_cast<const short8*>(kr);                     \
      dst[nt][1] = *reinterpret_cast<const short8*>(kr + 32);                \
    }                                                                        \
  }
#define SUMK(src)                                                            \
  {                                                                          \
    _Pragma("unroll") for (int nt = 0; nt < 4; ++nt) {                       \
      floatx4 acc = {0.f, 0.f, 0.f, 0.f};                                    \
      acc = __builtin_amdgcn_mfma_f32_16x16x32_bf16(src[nt][0], qf0, acc, 0, 0, 0); \
      acc = __builtin_amdgcn_mfma_f32_16x16x32_bf16(src[nt][1], qf1, acc, 0, 0, 0); \
      _Pragma("unroll") for (int r = 0; r < 4; ++r)                          \
          lsum += __builtin_amdgcn_exp2f(acc[r] * SM_COEF);                  \
    }                                                                        \
  }
  float lsum = 0.f;
  LOADK(ka, 0);
  for (int t = 0; t < 32; t += 2) {
    if (t + 1 < 32) LOADK(kc, t + 1);
    SUMK(ka);
    if (t + 2 < 32) LOADK(ka, t + 2);
    if (t + 1 < 32) SUMK(kc);
  }
  // lane holds partial sum for row i = itile + l15; merge the 4 g-lanes
  lsum += __shfl_xor(lsum, 16, 64);
  lsum += __shfl_xor(lsum, 32, 64);
  const float linv = 1.0f / lsum;

  // ---- phase 2: recompute S^T, stream P (float4), accumulate O^T = V^T * P^T ----
  floatx4 oacc[4];
#pragma unroll
  for (int mt = 0; mt < 4; ++mt) oacc[mt] = (floatx4){0.f, 0.f, 0.f, 0.f};

  float* prow = out + (size_t)BB * 512 * LL + ((size_t)bh * LL + itile + l15) * LL;
  unsigned char* wb = &pls[wave][0];

  for (int t = 0; t < 32; ++t) {
    const int j0 = t * 64;
    short8 kf[4][2];
    LOADK(kf, t);
#pragma unroll
    for (int nt = 0; nt < 4; ++nt) {
      floatx4 acc = {0.f, 0.f, 0.f, 0.f};
      acc = __builtin_amdgcn_mfma_f32_16x16x32_bf16(kf[nt][0], qf0, acc, 0, 0, 0);
      acc = __builtin_amdgcn_mfma_f32_16x16x32_bf16(kf[nt][1], qf1, acc, 0, 0, 0);
      // lane holds P[i = itile+l15][j = j0 + nt*16 + 4g + r], r = 0..3 consecutive
      float4 pw;
      __hip_bfloat16 hb[4] __attribute__((aligned(8)));
#pragma unroll
      for (int r = 0; r < 4; ++r) {
        const float p = __builtin_amdgcn_exp2f(acc[r] * SM_COEF) * linv;
        (&pw.x)[r] = p;
        hb[r] = __float2bfloat16(p);
      }
      *reinterpret_cast<float4*>(prow + j0 + nt * 16 + 4 * g) = pw;
      *reinterpret_cast<u64*>(wb + l15 * 128 + ((nt * 32 + g * 8) ^ swz)) =
          *reinterpret_cast<const u64*>(hb);
    }
    // wave-private LDS exchange: fence DS writes -> DS reads (no block barrier needed)
    asm volatile("s_waitcnt lgkmcnt(0)" ::: "memory");
    __builtin_amdgcn_sched_barrier(0);
    // PV: O^T[d][i] += V^T[d][j] * P^T[j][i]
#pragma unroll
    for (int ks = 0; ks < 2; ++ks) {
      const short8 pb = *reinterpret_cast<const short8*>(
          wb + l15 * 128 + ((ks * 64 + g * 16) ^ swz));
      const u16* vc = vbase + (size_t)l15 * LL + j0 + ks * 32 + 8 * g;
#pragma unroll
      for (int mt = 0; mt < 4; ++mt) {
        const short8 va = *reinterpret_cast<const short8*>(vc + (size_t)mt * 16 * LL);
        oacc[mt] = __builtin_amdgcn_mfma_f32_16x16x32_bf16(va, pb, oacc[mt], 0, 0, 0);
      }
    }
  }

  // O^T C-layout (row = d' = mt*16 + 4g + r, col = i = l15) -> out0 [b][h*64+d][i]
  float* obase = out + (size_t)(b * 512 + h * 64) * LL + itile + l15;
#pragma unroll
  for (int mt = 0; mt < 4; ++mt) {
#pragma unroll
    for (int r = 0; r < 4; ++r) {
      obase[(size_t)(mt * 16 + 4 * g + r) * LL] = oacc[mt][r];
    }
  }
}

extern "C" void kernel_launch(void* const* d_in, const int* in_sizes, int n_in,
                              void* d_out, int out_size, void* d_ws, size_t ws_size,
                              hipStream_t stream) {
  const float* x = (const float*)d_in[0];
  float* out = (float*)d_out;
  unsigned short* ws = (unsigned short*)d_ws;  // 3 * 4M bf16 = 24 MB
  unsigned short* qbuf = ws;
  unsigned short* kbuf = ws + (size_t)BB * HH * LL * DD;
  unsigned short* vbuf = ws + (size_t)2 * BB * HH * LL * DD;

  qk_tr_kernel<<<dim3(32, 16, 4), 256, 0, stream>>>(x, ws);
  v_cv_kernel<<<dim3(4096), 256, 0, stream>>>(x, vbuf);
  mha_main_kernel<<<dim3(1024), 256, 0, stream>>>(qbuf, kbuf, vbuf, out);
}

// Round 4
// 258.064 us; speedup vs baseline: 1.5999x; 1.5999x over previous
//
#include <hip/hip_runtime.h>
#include <hip/hip_bf16.h>

#define BB 4
#define HH 8
#define LL 2048
#define DD 64

typedef __attribute__((ext_vector_type(8))) short short8;
typedef __attribute__((ext_vector_type(4))) float floatx4;
typedef unsigned int u32;
typedef unsigned short u16;
typedef unsigned long long u64;

// 1/sqrt(DIM/HEADS) * log2(e) = (1/sqrt(8)) * 1.4426950409
#define SM_COEF 0.51006977f

#define WAITV(N) asm volatile("s_waitcnt vmcnt(" #N ")" ::: "memory")
#define LGKM0()  asm volatile("s_waitcnt lgkmcnt(0)" ::: "memory")
#define SCHED0() __builtin_amdgcn_sched_barrier(0)

__device__ __forceinline__ void gld_lds16(const void* g, void* l) {
  __builtin_amdgcn_global_load_lds((const __attribute__((address_space(1))) u32*)g,
                                   (__attribute__((address_space(3))) u32*)l, 16, 0, 0);
}

// ---- K0a: transpose+convert Q,K: x[b, g*512+h*64+d, i] -> ws[g][b][h][i][d] (bf16) ----
__global__ __launch_bounds__(256) void qk_tr_kernel(const float* __restrict__ x,
                                                    unsigned short* __restrict__ ws) {
  const int b = blockIdx.z;
  const int g = blockIdx.y >> 3;   // 0 = Q, 1 = K
  const int h = blockIdx.y & 7;
  const int tid = threadIdx.x;
  const int i = blockIdx.x * 64 + (tid & 63);
  const int dq = tid >> 6;         // which 16-row d-group
  const float* src = x + ((size_t)(b * 1536 + g * 512 + h * 64 + dq * 16)) * LL + i;
  float v[16];
#pragma unroll
  for (int k = 0; k < 16; ++k) v[k] = src[(size_t)k * LL];
  __hip_bfloat16 hb[16] __attribute__((aligned(16)));
#pragma unroll
  for (int k = 0; k < 16; ++k) hb[k] = __float2bfloat16(v[k]);
  unsigned short* dst = ws + (size_t)g * ((size_t)BB * HH * LL * DD) +
                        ((size_t)(b * HH + h) * LL + i) * DD + dq * 16;
  *reinterpret_cast<short8*>(dst) = *reinterpret_cast<const short8*>(hb);
  *reinterpret_cast<short8*>(dst + 8) = *reinterpret_cast<const short8*>(hb + 8);
}

// ---- K0b: straight convert V: x[b, 1024+h*64+d, j] -> vt[b][h][d][j] (bf16) ----
__global__ __launch_bounds__(256) void v_cv_kernel(const float* __restrict__ x,
                                                   unsigned short* __restrict__ vt) {
  const size_t idx = ((size_t)blockIdx.x * 256 + threadIdx.x) * 4;  // over B*512*L floats
  const size_t row = idx >> 11;   // b*512 + (h*64+d)
  const int col = (int)(idx & 2047);
  const size_t b = row >> 9;
  const size_t r = row & 511;
  const float4 f = *reinterpret_cast<const float4*>(x + ((b * 1536 + 1024 + r) << 11) + col);
  __hip_bfloat16 hb[4] __attribute__((aligned(8)));
  hb[0] = __float2bfloat16(f.x);
  hb[1] = __float2bfloat16(f.y);
  hb[2] = __float2bfloat16(f.z);
  hb[3] = __float2bfloat16(f.w);
  *reinterpret_cast<u64*>(vt + idx) = *reinterpret_cast<const u64*>(hb);
}

// ---- K1: fused attention. 1024 blocks (XCD-swizzled), 4 waves x 16 i-rows each.
//      Shared K staging via global_load_lds, 3-buf 2-deep, raw barrier + counted vmcnt. ----
__global__ __launch_bounds__(256, 4) void mha_main_kernel(const u16* __restrict__ qb,
                                                          const u16* __restrict__ kb,
                                                          const u16* __restrict__ vt,
                                                          float* __restrict__ out) {
  __shared__ u16 kbuf[3][4096] __attribute__((aligned(16)));           // 3 x (64 rows x 128B)
  __shared__ unsigned char pls[4][2048] __attribute__((aligned(16)));  // per-wave 16x64 bf16 P

  // XCD-bijective swizzle: each XCD owns 4 consecutive (b,h) (1024 % 8 == 0)
  const int wg = blockIdx.x;
  const int lin = (wg & 7) * 128 + (wg >> 3);
  const int bh = lin >> 5;          // 0..31
  const int ib = lin & 31;          // i-block within (b,h)
  const int b = bh >> 3, h = bh & 7;

  const int tid = threadIdx.x;
  const int wave = tid >> 6, lane = tid & 63;
  const int l15 = lane & 15, g = lane >> 4;
  const int swz = (l15 & 7) << 4;
  const int itile = ib * 64 + wave * 16;

  // Q B-fragments (col = l15 -> i, k = 8*g+t -> d), kept in registers
  const u16* qrow = qb + ((size_t)bh * LL + itile + l15) * DD + 8 * g;
  const short8 qf0 = *reinterpret_cast<const short8*>(qrow);
  const short8 qf1 = *reinterpret_cast<const short8*>(qrow + 32);
  const u16* ktile = kb + (size_t)bh * LL * DD;   // K [j][d] staging base
  const u16* vbase = vt + (size_t)bh * DD * LL;   // V [d][j]

  // stage K tile (64 rows) into kbuf[bsel]; source pre-swizzled so swizzled
  // ds_read_b128 fragment reads are bank-conflict-free (m173 pattern)
  auto stageK = [&](int bsel, int tidx) {
    const char* src = (const char*)(ktile + (size_t)tidx * 64 * DD);
#pragma unroll
    for (int q = 0; q < 2; ++q) {
      const int o = wave * 2048 + q * 1024 + lane * 16;
      const int row = o >> 7;
      const int so = (o & ~127) | ((o & 127) ^ ((row & 7) << 4));
      gld_lds16(src + so, (char*)(&kbuf[bsel][0]) + wave * 2048 + q * 1024);
    }
  };

  // ---- phase 1: row sum of exp2 (|s*log2e| <~ 25 fits fp32; no max tracking) ----
  float lsum = 0.f;
  stageK(0, 0);
  stageK(1, 1);
  for (int t = 0; t < 32; ++t) {
    WAITV(2);                       // stage(t) done; stage(t+1) may fly
    __builtin_amdgcn_s_barrier();
    SCHED0();
    stageK((t + 2) % 3, (t + 2) & 31);   // dummy wrap at tail keeps counts uniform
    const char* kbb = (const char*)(&kbuf[t % 3][0]);
#pragma unroll
    for (int nt = 0; nt < 4; ++nt) {
      const char* kr = kbb + (nt * 16 + l15) * 128;
      const short8 kf0 = *reinterpret_cast<const short8*>(kr + ((g * 16) ^ swz));
      const short8 kf1 = *reinterpret_cast<const short8*>(kr + ((64 + g * 16) ^ swz));
      floatx4 acc = {0.f, 0.f, 0.f, 0.f};
      acc = __builtin_amdgcn_mfma_f32_16x16x32_bf16(kf0, qf0, acc, 0, 0, 0);
      acc = __builtin_amdgcn_mfma_f32_16x16x32_bf16(kf1, qf1, acc, 0, 0, 0);
#pragma unroll
      for (int r = 0; r < 4; ++r) lsum += __builtin_amdgcn_exp2f(acc[r] * SM_COEF);
    }
  }
  // lane holds partial sum for row i = itile + l15; merge the 4 g-lanes
  lsum += __shfl_xor(lsum, 16, 64);
  lsum += __shfl_xor(lsum, 32, 64);
  const float linv = 1.0f / lsum;

  __syncthreads();  // phase boundary: drain all DMA before re-staging

  // ---- phase 2: recompute S^T, stream P (float4), accumulate O^T = V^T * P^T ----
  floatx4 oacc[4];
#pragma unroll
  for (int mt = 0; mt < 4; ++mt) oacc[mt] = (floatx4){0.f, 0.f, 0.f, 0.f};

  float* prow = out + (size_t)BB * 512 * LL + ((size_t)bh * LL + itile + l15) * LL;
  unsigned char* wb = &pls[wave][0];

  stageK(0, 0);
  stageK(1, 1);
  for (int t = 0; t < 32; ++t) {
    // per iter VMEM issue: stage.2, Vload.8, Pstore.4 (=14). Ensure stage(t) done:
    // newer ops = 26 (t>=2), 14 (t==1), 2 (t==0). P stores ride across barriers.
    if (t == 0) { WAITV(2); } else if (t == 1) { WAITV(14); } else { WAITV(26); }
    __builtin_amdgcn_s_barrier();
    SCHED0();
    stageK((t + 2) % 3, (t + 2) & 31);
    const int j0 = t * 64;
    // V prefetch early (T14): consumed after QK^T with only P stores newer (vmcnt(4))
    short8 vfa[4], vfb[4];
    const u16* vc = vbase + (size_t)l15 * LL + j0 + 8 * g;
#pragma unroll
    for (int mt = 0; mt < 4; ++mt) {
      vfa[mt] = *reinterpret_cast<const short8*>(vc + (size_t)mt * 16 * LL);
      vfb[mt] = *reinterpret_cast<const short8*>(vc + (size_t)mt * 16 * LL + 32);
    }
    SCHED0();
    const char* kbb = (const char*)(&kbuf[t % 3][0]);
#pragma unroll
    for (int nt = 0; nt < 4; ++nt) {
      const char* kr = kbb + (nt * 16 + l15) * 128;
      const short8 kf0 = *reinterpret_cast<const short8*>(kr + ((g * 16) ^ swz));
      const short8 kf1 = *reinterpret_cast<const short8*>(kr + ((64 + g * 16) ^ swz));
      floatx4 acc = {0.f, 0.f, 0.f, 0.f};
      acc = __builtin_amdgcn_mfma_f32_16x16x32_bf16(kf0, qf0, acc, 0, 0, 0);
      acc = __builtin_amdgcn_mfma_f32_16x16x32_bf16(kf1, qf1, acc, 0, 0, 0);
      // lane holds P[i = itile+l15][j = j0 + nt*16 + 4g + r], r = 0..3 consecutive
      float4 pw;
      __hip_bfloat16 hb[4] __attribute__((aligned(8)));
#pragma unroll
      for (int r = 0; r < 4; ++r) {
        const float p = __builtin_amdgcn_exp2f(acc[r] * SM_COEF) * linv;
        (&pw.x)[r] = p;
        hb[r] = __float2bfloat16(p);
      }
      *reinterpret_cast<float4*>(prow + j0 + nt * 16 + 4 * g) = pw;
      *reinterpret_cast<u64*>(wb + l15 * 128 + ((nt * 32 + g * 8) ^ swz)) =
          *reinterpret_cast<const u64*>(hb);
    }
    // wave-private LDS exchange: fence DS writes -> DS reads (rule 18)
    LGKM0();
    SCHED0();
    // PV: O^T[d][i] += V^T[d][j] * P^T[j][i]
#pragma unroll
    for (int ks = 0; ks < 2; ++ks) {
      const short8 pb = *reinterpret_cast<const short8*>(
          wb + l15 * 128 + ((ks * 64 + g * 16) ^ swz));
#pragma unroll
      for (int mt = 0; mt < 4; ++mt) {
        oacc[mt] = __builtin_amdgcn_mfma_f32_16x16x32_bf16(
            ks == 0 ? vfa[mt] : vfb[mt], pb, oacc[mt], 0, 0, 0);
      }
    }
  }

  // O^T C-layout (row = d' = mt*16 + 4g + r, col = i = l15) -> out0 [b][h*64+d][i]
  float* obase = out + (size_t)(b * 512 + h * 64) * LL + itile + l15;
#pragma unroll
  for (int mt = 0; mt < 4; ++mt) {
#pragma unroll
    for (int r = 0; r < 4; ++r) {
      obase[(size_t)(mt * 16 + 4 * g + r) * LL] = oacc[mt][r];
    }
  }
}

extern "C" void kernel_launch(void* const* d_in, const int* in_sizes, int n_in,
                              void* d_out, int out_size, void* d_ws, size_t ws_size,
                              hipStream_t stream) {
  const float* x = (const float*)d_in[0];
  float* out = (float*)d_out;
  unsigned short* ws = (unsigned short*)d_ws;  // 3 * 4M bf16 = 24 MB
  unsigned short* qbuf = ws;
  unsigned short* kbuf = ws + (size_t)BB * HH * LL * DD;
  unsigned short* vbuf = ws + (size_t)2 * BB * HH * LL * DD;

  qk_tr_kernel<<<dim3(32, 16, 4), 256, 0, stream>>>(x, ws);
  v_cv_kernel<<<dim3(4096), 256, 0, stream>>>(x, vbuf);
  mha_main_kernel<<<dim3(1024), 256, 0, stream>>>(qbuf, kbuf, vbuf, out);
}